// Round 1
// baseline (1134.811 us; speedup 1.0000x reference)
//
#include <hip/hip_runtime.h>

typedef __bf16 bf16x8 __attribute__((ext_vector_type(8)));
typedef float f32x4 __attribute__((ext_vector_type(4)));

static constexpr int Bb = 4, Ss = 2048, Ee = 1024, Hh = 16, DKk = 64, DVv = 128;
static constexpr int Mm = Bb * Ss;   // 8192
static constexpr int NQ = Hh * DKk;  // 1024
static constexpr int NV = Hh * DVv;  // 2048

static __device__ __forceinline__ unsigned short f2b(float f) {
  unsigned int u = __float_as_uint(f);
  u += 0x7fffu + ((u >> 16) & 1u);
  return (unsigned short)(u >> 16);
}

__global__ __launch_bounds__(256) void cast_x_kernel(const float* __restrict__ in,
                                                     unsigned short* __restrict__ out, int n4) {
  int i = blockIdx.x * 256 + threadIdx.x;
  if (i >= n4) return;
  float4 v = reinterpret_cast<const float4*>(in)[i];
  ushort4 o;
  o.x = f2b(v.x); o.y = f2b(v.y); o.z = f2b(v.z); o.w = f2b(v.w);
  reinterpret_cast<ushort4*>(out)[i] = o;
}

// in: [Bt][R][C] f32  ->  out: [Bt][C][R] bf16
__global__ __launch_bounds__(256) void transpose_cast_kernel(const float* __restrict__ in,
                                                             unsigned short* __restrict__ out,
                                                             int R, int C) {
  __shared__ float tile[32][33];
  int c0 = blockIdx.x * 32, r0 = blockIdx.y * 32;
  const float* ip = in + (size_t)blockIdx.z * R * C;
  unsigned short* op = out + (size_t)blockIdx.z * R * C;
  int tx = threadIdx.x, ty = threadIdx.y;
#pragma unroll
  for (int i = 0; i < 32; i += 8)
    tile[ty + i][tx] = ip[(size_t)(r0 + ty + i) * C + (c0 + tx)];
  __syncthreads();
#pragma unroll
  for (int i = 0; i < 32; i += 8)
    op[(size_t)(c0 + ty + i) * R + (r0 + tx)] = f2b(tile[tx][ty + i]);
}

// C[M][N] = A[M][K] * BT[N][K]^T + bias[N]; 128x128 tile, BK=32, 4 waves.
template <bool F32OUT>
__global__ __launch_bounds__(256) void gemm_bt_kernel(const unsigned short* __restrict__ A,
                                                      const unsigned short* __restrict__ BT,
                                                      const float* __restrict__ bias,
                                                      void* __restrict__ Cout,
                                                      int M, int N, int K) {
  __shared__ unsigned short As[128 * 32];
  __shared__ unsigned short Bs[128 * 32];
  const int tid = threadIdx.x;
  const int wave = tid >> 6, lane = tid & 63;
  const int wr = wave >> 1, wc = wave & 1;
  const int l15 = lane & 15, lq = lane >> 4;
  const int bm = blockIdx.x * 128, bn = blockIdx.y * 128;

  f32x4 acc[4][4] = {};

  const int m0c = tid >> 2;        // chunk row
  const int kkc = (tid & 3) << 3;  // chunk k-offset

  for (int k0 = 0; k0 < K; k0 += 32) {
    int4 ra0 = *reinterpret_cast<const int4*>(A + (size_t)(bm + m0c) * K + k0 + kkc);
    int4 ra1 = *reinterpret_cast<const int4*>(A + (size_t)(bm + 64 + m0c) * K + k0 + kkc);
    int4 rb0 = *reinterpret_cast<const int4*>(BT + (size_t)(bn + m0c) * K + k0 + kkc);
    int4 rb1 = *reinterpret_cast<const int4*>(BT + (size_t)(bn + 64 + m0c) * K + k0 + kkc);
    __syncthreads();
    *reinterpret_cast<int4*>(&As[(size_t)tid * 8]) = ra0;
    *reinterpret_cast<int4*>(&As[(size_t)(tid + 256) * 8]) = ra1;
    *reinterpret_cast<int4*>(&Bs[(size_t)tid * 8]) = rb0;
    *reinterpret_cast<int4*>(&Bs[(size_t)(tid + 256) * 8]) = rb1;
    __syncthreads();
    bf16x8 af[4], bfr[4];
#pragma unroll
    for (int mi = 0; mi < 4; ++mi)
      af[mi] = *reinterpret_cast<const bf16x8*>(&As[(wr * 64 + mi * 16 + l15) * 32 + (lq << 3)]);
#pragma unroll
    for (int ni = 0; ni < 4; ++ni)
      bfr[ni] = *reinterpret_cast<const bf16x8*>(&Bs[(wc * 64 + ni * 16 + l15) * 32 + (lq << 3)]);
#pragma unroll
    for (int mi = 0; mi < 4; ++mi)
#pragma unroll
      for (int ni = 0; ni < 4; ++ni)
        acc[mi][ni] = __builtin_amdgcn_mfma_f32_16x16x32_bf16(af[mi], bfr[ni], acc[mi][ni], 0, 0, 0);
  }
#pragma unroll
  for (int ni = 0; ni < 4; ++ni) {
    int col = bn + wc * 64 + ni * 16 + l15;
    float bs = bias[col];
#pragma unroll
    for (int mi = 0; mi < 4; ++mi) {
      int row0 = bm + wr * 64 + mi * 16 + (lq << 2);
#pragma unroll
      for (int r = 0; r < 4; ++r) {
        float v = acc[mi][ni][r] + bs;
        if (F32OUT)
          reinterpret_cast<float*>(Cout)[(size_t)(row0 + r) * N + col] = v;
        else
          reinterpret_cast<unsigned short*>(Cout)[(size_t)(row0 + r) * N + col] = f2b(v);
      }
    }
  }
}

// Flash attention, causal. Q/K: [B,S,H,DK] bf16, V: [B,S,H,DV] bf16, out A: [B,S,H*DV] bf16.
// Block: 256 thr / 4 waves; q-tile 64 rows (16 per wave); kv-tile 64.
__global__ __launch_bounds__(256) void attn_kernel(const unsigned short* __restrict__ Qw,
                                                   const unsigned short* __restrict__ Kw,
                                                   const unsigned short* __restrict__ Vw,
                                                   unsigned short* __restrict__ Aw) {
  __shared__ unsigned short Ks[64 * 64];    // [kv][d], chunk-swizzled: slot = (d>>3)^(kv&7)
  __shared__ unsigned short VTs[128 * 64];  // [dv][kv], slot = (kv>>3)^(dv&7)^((dv>>3)&7)
  __shared__ unsigned short Ps[4][16 * 64]; // per-wave [qr][kv], slot = (kv>>3)^(qr&7)
  const int qt = blockIdx.x, h = blockIdx.y, b = blockIdx.z;
  const int tid = threadIdx.x, wave = tid >> 6, lane = tid & 63;
  const int l15 = lane & 15, lq = lane >> 4;
  const int qbase = qt * 64;

  const int qrow = qbase + wave * 16 + l15;
  const unsigned short* qptr = Qw + ((size_t)(b * Ss + qrow) * Hh + h) * DKk + (lq << 3);
  bf16x8 qf[2];
  qf[0] = *reinterpret_cast<const bf16x8*>(qptr);
  qf[1] = *reinterpret_cast<const bf16x8*>(qptr + 32);

  f32x4 accO[8] = {};
  float mrow[4] = {-1e30f, -1e30f, -1e30f, -1e30f};
  float lrow[4] = {0.f, 0.f, 0.f, 0.f};
  const float LOG2E = 1.44269504088896f;

  const unsigned short* Ksrc0 = Kw + ((size_t)(b * Ss) * Hh + h) * DKk;
  const unsigned short* Vsrc0 = Vw + ((size_t)(b * Ss) * Hh + h) * DVv;

  for (int kt = 0; kt <= qt; ++kt) {
    const int kbase = kt * 64;
    __syncthreads();
    // stage K (64x64), swizzled chunks, linear LDS stores
#pragma unroll
    for (int i = 0; i < 2; ++i) {
      int c = (i << 8) + tid;
      int kv = c >> 3, w8 = c & 7;
      int dc = w8 ^ (kv & 7);
      int4 kd = *reinterpret_cast<const int4*>(Ksrc0 + (size_t)(kbase + kv) * NQ + (dc << 3));
      *reinterpret_cast<int4*>(&Ks[c << 3]) = kd;
    }
    // stage V transposed (dv-major), swizzled
#pragma unroll
    for (int i = 0; i < 4; ++i) {
      int kv = (wave << 4) + (i << 2) + (tid & 3);
      int dv0 = ((tid >> 2) & 15) << 3;
      int4 vd = *reinterpret_cast<const int4*>(Vsrc0 + (size_t)(kbase + kv) * NV + dv0);
      const unsigned short* vs = reinterpret_cast<const unsigned short*>(&vd);
#pragma unroll
      for (int j = 0; j < 8; ++j) {
        int dv = dv0 + j;
        int chunk = ((kv >> 3) ^ (dv & 7) ^ ((dv >> 3) & 7)) & 7;
        VTs[dv * 64 + chunk * 8 + (kv & 7)] = vs[j];
      }
    }
    __syncthreads();
    // QK^T: scores [16 q][64 kv] per wave
    f32x4 accS[4] = {};
#pragma unroll
    for (int kc = 0; kc < 2; ++kc) {
      int dloc = (kc << 5) + (lq << 3);
#pragma unroll
      for (int ni = 0; ni < 4; ++ni) {
        int kvl = ni * 16 + l15;
        int chunk = ((dloc >> 3) ^ (kvl & 7)) & 7;
        bf16x8 kf = *reinterpret_cast<const bf16x8*>(&Ks[kvl * 64 + chunk * 8]);
        accS[ni] = __builtin_amdgcn_mfma_f32_16x16x32_bf16(qf[kc], kf, accS[ni], 0, 0, 0);
      }
    }
    // online softmax
    float sv[4][4];
#pragma unroll
    for (int ni = 0; ni < 4; ++ni)
#pragma unroll
      for (int r = 0; r < 4; ++r) {
        float s = accS[ni][r] * 0.125f;
        if (kt == qt) {
          int rowr = wave * 16 + (lq << 2) + r;
          int colr = ni * 16 + l15;
          if (colr > rowr) s = -1e30f;
        }
        sv[ni][r] = s;
      }
    float mnew[4], al[4];
#pragma unroll
    for (int r = 0; r < 4; ++r) {
      float m = fmaxf(fmaxf(sv[0][r], sv[1][r]), fmaxf(sv[2][r], sv[3][r]));
      m = fmaxf(m, __shfl_xor(m, 1));
      m = fmaxf(m, __shfl_xor(m, 2));
      m = fmaxf(m, __shfl_xor(m, 4));
      m = fmaxf(m, __shfl_xor(m, 8));
      float mn = fmaxf(mrow[r], m);
      mnew[r] = mn;
      al[r] = exp2f((mrow[r] - mn) * LOG2E);
    }
    float pv[4][4], rs[4] = {0.f, 0.f, 0.f, 0.f};
#pragma unroll
    for (int ni = 0; ni < 4; ++ni)
#pragma unroll
      for (int r = 0; r < 4; ++r) {
        float p = exp2f((sv[ni][r] - mnew[r]) * LOG2E);
        pv[ni][r] = p;
        rs[r] += p;
      }
#pragma unroll
    for (int r = 0; r < 4; ++r) {
      float t = rs[r];
      t += __shfl_xor(t, 1);
      t += __shfl_xor(t, 2);
      t += __shfl_xor(t, 4);
      t += __shfl_xor(t, 8);
      lrow[r] = lrow[r] * al[r] + t;
      mrow[r] = mnew[r];
    }
#pragma unroll
    for (int ni = 0; ni < 8; ++ni) {
      f32x4 o = accO[ni];
      o[0] *= al[0]; o[1] *= al[1]; o[2] *= al[2]; o[3] *= al[3];
      accO[ni] = o;
    }
    // P -> LDS (bf16, swizzled), per-wave region (DS unit is in-order per wave)
#pragma unroll
    for (int ni = 0; ni < 4; ++ni)
#pragma unroll
      for (int r = 0; r < 4; ++r) {
        int row = (lq << 2) + r;
        int col = ni * 16 + l15;
        int chunk = ((col >> 3) ^ (row & 7)) & 7;
        Ps[wave][row * 64 + chunk * 8 + (col & 7)] = f2b(pv[ni][r]);
      }
    // PV
#pragma unroll
    for (int kc = 0; kc < 2; ++kc) {
      int krel = (kc << 5) + (lq << 3);
      int pchunk = ((krel >> 3) ^ (l15 & 7)) & 7;
      bf16x8 pf = *reinterpret_cast<const bf16x8*>(&Ps[wave][l15 * 64 + pchunk * 8]);
#pragma unroll
      for (int ni = 0; ni < 8; ++ni) {
        int dv = ni * 16 + l15;
        int vchunk = ((krel >> 3) ^ (dv & 7) ^ ((dv >> 3) & 7)) & 7;
        bf16x8 vf = *reinterpret_cast<const bf16x8*>(&VTs[dv * 64 + vchunk * 8]);
        accO[ni] = __builtin_amdgcn_mfma_f32_16x16x32_bf16(pf, vf, accO[ni], 0, 0, 0);
      }
    }
  }
  // epilogue: normalize + store
#pragma unroll
  for (int ni = 0; ni < 8; ++ni) {
    int dv = ni * 16 + l15;
#pragma unroll
    for (int r = 0; r < 4; ++r) {
      int row = qbase + wave * 16 + (lq << 2) + r;
      Aw[(size_t)(b * Ss + row) * NV + h * DVv + dv] = f2b(accO[ni][r] / lrow[r]);
    }
  }
}

extern "C" void kernel_launch(void* const* d_in, const int* in_sizes, int n_in,
                              void* d_out, int out_size, void* d_ws, size_t ws_size,
                              hipStream_t stream) {
  (void)in_sizes; (void)n_in; (void)out_size; (void)ws_size;
  const float* x  = (const float*)d_in[0];
  const float* Wq = (const float*)d_in[1];
  const float* bq = (const float*)d_in[2];
  const float* Wk = (const float*)d_in[3];
  const float* bk = (const float*)d_in[4];
  const float* Wv = (const float*)d_in[5];
  const float* bv = (const float*)d_in[6];
  const float* Wo = (const float*)d_in[7];
  const float* bo = (const float*)d_in[8];
  float* out = (float*)d_out;

  unsigned short* ws = (unsigned short*)d_ws;
  unsigned short* xb  = ws;                    // 8388608  (x bf16 [8192][1024])
  unsigned short* WqT = xb  + 8388608;         // 1048576  ([H*DK][E])
  unsigned short* WkT = WqT + 1048576;         // 1048576
  unsigned short* WvT = WkT + 1048576;         // 2097152  ([H*DV][E])
  unsigned short* WoT = WvT + 2097152;         // 2097152  ([E][H*DV])
  unsigned short* Qw  = WoT + 2097152;         // 8388608  ([B,S,H,DK])
  unsigned short* Kw  = Qw  + 8388608;         // 8388608
  unsigned short* Vw  = Kw  + 8388608;         // 16777216 ([B,S,H,DV])
  unsigned short* Aw  = Vw  + 16777216;        // 16777216 ([B,S,H*DV])

  cast_x_kernel<<<dim3(8192), dim3(256), 0, stream>>>(x, xb, (Mm * Ee) / 4);

  transpose_cast_kernel<<<dim3(2, 32, 16), dim3(32, 8), 0, stream>>>(Wq, WqT, Ee, DKk);
  transpose_cast_kernel<<<dim3(2, 32, 16), dim3(32, 8), 0, stream>>>(Wk, WkT, Ee, DKk);
  transpose_cast_kernel<<<dim3(4, 32, 16), dim3(32, 8), 0, stream>>>(Wv, WvT, Ee, DVv);
  transpose_cast_kernel<<<dim3(32, 64, 1), dim3(32, 8), 0, stream>>>(Wo, WoT, NV, Ee);

  gemm_bt_kernel<false><<<dim3(64, 8),  dim3(256), 0, stream>>>(xb, WqT, bq, Qw, Mm, NQ, Ee);
  gemm_bt_kernel<false><<<dim3(64, 8),  dim3(256), 0, stream>>>(xb, WkT, bk, Kw, Mm, NQ, Ee);
  gemm_bt_kernel<false><<<dim3(64, 16), dim3(256), 0, stream>>>(xb, WvT, bv, Vw, Mm, NV, Ee);

  attn_kernel<<<dim3(32, 16, 4), dim3(256), 0, stream>>>(Qw, Kw, Vw, Aw);

  gemm_bt_kernel<true><<<dim3(64, 8), dim3(256), 0, stream>>>(Aw, WoT, bo, out, Mm, NQ, NV);
}

// Round 2
// 589.057 us; speedup vs baseline: 1.9265x; 1.9265x over previous
//
#include <hip/hip_runtime.h>

typedef __bf16 bf16x8 __attribute__((ext_vector_type(8)));
typedef float f32x4 __attribute__((ext_vector_type(4)));

static constexpr int Bb = 4, Ss = 2048, Ee = 1024, Hh = 16, DKk = 64, DVv = 128;
static constexpr int Mm = Bb * Ss;   // 8192
static constexpr int NQ = Hh * DKk;  // 1024
static constexpr int NV = Hh * DVv;  // 2048

#define MFMA16 __builtin_amdgcn_mfma_f32_16x16x32_bf16

static __device__ __forceinline__ unsigned short f2b(float f) {
  unsigned int u = __float_as_uint(f);
  u += 0x7fffu + ((u >> 16) & 1u);
  return (unsigned short)(u >> 16);
}

__global__ __launch_bounds__(256) void cast_x_kernel(const float* __restrict__ in,
                                                     unsigned short* __restrict__ out, int n4) {
  int i = blockIdx.x * 256 + threadIdx.x;
  if (i >= n4) return;
  float4 v = reinterpret_cast<const float4*>(in)[i];
  ushort4 o;
  o.x = f2b(v.x); o.y = f2b(v.y); o.z = f2b(v.z); o.w = f2b(v.w);
  reinterpret_cast<ushort4*>(out)[i] = o;
}

// in: [Bt][R][C] f32  ->  out: [Bt][C][R] bf16
__global__ __launch_bounds__(256) void transpose_cast_kernel(const float* __restrict__ in,
                                                             unsigned short* __restrict__ out,
                                                             int R, int C) {
  __shared__ float tile[32][33];
  int c0 = blockIdx.x * 32, r0 = blockIdx.y * 32;
  const float* ip = in + (size_t)blockIdx.z * R * C;
  unsigned short* op = out + (size_t)blockIdx.z * R * C;
  int tx = threadIdx.x, ty = threadIdx.y;
#pragma unroll
  for (int i = 0; i < 32; i += 8)
    tile[ty + i][tx] = ip[(size_t)(r0 + ty + i) * C + (c0 + tx)];
  __syncthreads();
#pragma unroll
  for (int i = 0; i < 32; i += 8)
    op[(size_t)(c0 + ty + i) * R + (r0 + tx)] = f2b(tile[tx][ty + i]);
}

// C = A[M][K] * BT[N][K]^T + bias[N]; 128x128 tile, BK=32, 4 waves.
// OUTMODE: 0 = bf16 [M][N]; 1 = f32 [M][N]; 2 = bf16 Vt[B,H,DV,S] transposed write.
template <int OUTMODE>
__global__ __launch_bounds__(256) void gemm_bt_kernel(const unsigned short* __restrict__ A,
                                                      const unsigned short* __restrict__ BT,
                                                      const float* __restrict__ bias,
                                                      void* __restrict__ Cout,
                                                      int M, int N, int K) {
  __shared__ unsigned short As[128 * 32];
  __shared__ unsigned short Bs[128 * 32];
  const int tid = threadIdx.x;
  const int wave = tid >> 6, lane = tid & 63;
  const int wr = wave >> 1, wc = wave & 1;
  const int l15 = lane & 15, lq = lane >> 4;
  const int bm = blockIdx.x * 128, bn = blockIdx.y * 128;

  f32x4 acc[4][4] = {};

  const int m0c = tid >> 2;        // chunk row
  const int kkc = (tid & 3) << 3;  // chunk k-offset

  for (int k0 = 0; k0 < K; k0 += 32) {
    int4 ra0 = *reinterpret_cast<const int4*>(A + (size_t)(bm + m0c) * K + k0 + kkc);
    int4 ra1 = *reinterpret_cast<const int4*>(A + (size_t)(bm + 64 + m0c) * K + k0 + kkc);
    int4 rb0 = *reinterpret_cast<const int4*>(BT + (size_t)(bn + m0c) * K + k0 + kkc);
    int4 rb1 = *reinterpret_cast<const int4*>(BT + (size_t)(bn + 64 + m0c) * K + k0 + kkc);
    __syncthreads();
    *reinterpret_cast<int4*>(&As[(size_t)tid * 8]) = ra0;
    *reinterpret_cast<int4*>(&As[(size_t)(tid + 256) * 8]) = ra1;
    *reinterpret_cast<int4*>(&Bs[(size_t)tid * 8]) = rb0;
    *reinterpret_cast<int4*>(&Bs[(size_t)(tid + 256) * 8]) = rb1;
    __syncthreads();
    bf16x8 af[4], bfr[4];
#pragma unroll
    for (int mi = 0; mi < 4; ++mi)
      af[mi] = *reinterpret_cast<const bf16x8*>(&As[(wr * 64 + mi * 16 + l15) * 32 + (lq << 3)]);
#pragma unroll
    for (int ni = 0; ni < 4; ++ni)
      bfr[ni] = *reinterpret_cast<const bf16x8*>(&Bs[(wc * 64 + ni * 16 + l15) * 32 + (lq << 3)]);
#pragma unroll
    for (int mi = 0; mi < 4; ++mi)
#pragma unroll
      for (int ni = 0; ni < 4; ++ni)
        acc[mi][ni] = MFMA16(af[mi], bfr[ni], acc[mi][ni], 0, 0, 0);
  }
#pragma unroll
  for (int ni = 0; ni < 4; ++ni) {
    int col = bn + wc * 64 + ni * 16 + l15;
    float bs = bias[col];
#pragma unroll
    for (int mi = 0; mi < 4; ++mi) {
      int row0 = bm + wr * 64 + mi * 16 + (lq << 2);
      if (OUTMODE == 2) {
        int b_ = row0 >> 11, s0 = row0 & 2047;
        unsigned short* dst = (unsigned short*)Cout +
            ((size_t)((b_ * Hh + (col >> 7)) * DVv + (col & 127))) * Ss + s0;
        ushort4 o;
        o.x = f2b(acc[mi][ni][0] + bs);
        o.y = f2b(acc[mi][ni][1] + bs);
        o.z = f2b(acc[mi][ni][2] + bs);
        o.w = f2b(acc[mi][ni][3] + bs);
        *reinterpret_cast<ushort4*>(dst) = o;
      } else {
#pragma unroll
        for (int r = 0; r < 4; ++r) {
          float v = acc[mi][ni][r] + bs;
          if (OUTMODE == 1)
            reinterpret_cast<float*>(Cout)[(size_t)(row0 + r) * N + col] = v;
          else
            reinterpret_cast<unsigned short*>(Cout)[(size_t)(row0 + r) * N + col] = f2b(v);
        }
      }
    }
  }
}

// Flash attention, causal, swapped-QK^T. Q/K: [B,S,H,DK] bf16; Vt: [B,H,DV,S] bf16;
// out Aw: [B,S,H*DV] bf16. 4 waves; q-tile 128 (32 rows/wave); kv-tile 64.
__global__ __launch_bounds__(256) void attn2_kernel(const unsigned short* __restrict__ Qw,
                                                    const unsigned short* __restrict__ Kw,
                                                    const unsigned short* __restrict__ Vt,
                                                    unsigned short* __restrict__ Aw) {
  __shared__ unsigned short Ks[64 * 64];     // [kv][d], 16B-chunk slot = ch ^ (kv&7)
  __shared__ unsigned short VTs[128 * 64];   // [dv][kv], slot = ch ^ (dv&7)
  __shared__ unsigned short Ps[4][32 * 64];  // per-wave [q][kv], slot = c ^ (q&7)
  const int qt = blockIdx.x, h = blockIdx.y, b = blockIdx.z;
  const int tid = threadIdx.x, wave = tid >> 6, lane = tid & 63;
  const int l15 = lane & 15, lq = lane >> 4;
  const int qbase = qt * 128;
  const int ktmax = 2 * qt + 2;
  const float SCL = 0.125f * 1.44269504088896f;  // scale * log2(e); exp2 domain throughout

  // Q fragments (B-operand of swapped QK): col=l15 -> q row, k = kc*32+lq*8+j
  bf16x8 qf[2][2];
#pragma unroll
  for (int qm = 0; qm < 2; ++qm) {
    int qrow = qbase + wave * 32 + qm * 16 + l15;
    const unsigned short* qp = Qw + ((size_t)(b * Ss + qrow) * Hh + h) * DKk + (lq << 3);
    qf[qm][0] = *reinterpret_cast<const bf16x8*>(qp);
    qf[qm][1] = *reinterpret_cast<const bf16x8*>(qp + 32);
  }

  const unsigned short* Ksrc = Kw + ((size_t)(b * Ss) * Hh + h) * DKk;
  const unsigned short* Vsrc = Vt + ((size_t)(b * Hh + h)) * DVv * Ss;

  const int row_s = tid >> 3;  // staging: row within 32-row group
  const int ch_s = tid & 7;    // staging: 16B chunk slot (LDS side, linear)

  f32x4 accO[2][8] = {};
  float mrow[2] = {-1e30f, -1e30f}, lrow[2] = {0.f, 0.f};

  // prologue: stage tile 0 into regs (source-side swizzle -> linear LDS writes)
  int4 kreg[2], vreg[4];
#pragma unroll
  for (int i = 0; i < 2; ++i) {
    int kv = i * 32 + row_s;
    kreg[i] = *reinterpret_cast<const int4*>(Ksrc + (size_t)kv * NQ + ((ch_s ^ (kv & 7)) << 3));
  }
#pragma unroll
  for (int i = 0; i < 4; ++i) {
    int dv = i * 32 + row_s;
    vreg[i] = *reinterpret_cast<const int4*>(Vsrc + (size_t)dv * Ss + ((ch_s ^ (dv & 7)) << 3));
  }

  for (int kt = 0; kt < ktmax; ++kt) {
    const int kbase = kt * 64;
    __syncthreads();  // previous tile's LDS reads done
#pragma unroll
    for (int i = 0; i < 2; ++i)
      *reinterpret_cast<int4*>(&Ks[((i << 8) + tid) << 3]) = kreg[i];
#pragma unroll
    for (int i = 0; i < 4; ++i)
      *reinterpret_cast<int4*>(&VTs[((i << 8) + tid) << 3]) = vreg[i];
    __syncthreads();
    // T14: issue next tile's loads now; latency hides under compute below
    if (kt + 1 < ktmax) {
      const int nb = kbase + 64;
#pragma unroll
      for (int i = 0; i < 2; ++i) {
        int kv = i * 32 + row_s;
        kreg[i] = *reinterpret_cast<const int4*>(Ksrc + (size_t)(nb + kv) * NQ + ((ch_s ^ (kv & 7)) << 3));
      }
#pragma unroll
      for (int i = 0; i < 4; ++i) {
        int dv = i * 32 + row_s;
        vreg[i] = *reinterpret_cast<const int4*>(Vsrc + (size_t)dv * Ss + nb + ((ch_s ^ (dv & 7)) << 3));
      }
    }
    // QK^T swapped: S^T[kv][q]; lane: q = l15(+qm*16), kv = f*16 + lq*4 + r
    f32x4 accS[2][4] = {};
#pragma unroll
    for (int kc = 0; kc < 2; ++kc) {
#pragma unroll
      for (int f = 0; f < 4; ++f) {
        int kvl = f * 16 + l15;
        int ch = (kc * 4 + lq) ^ (kvl & 7);
        bf16x8 kf = *reinterpret_cast<const bf16x8*>(&Ks[kvl * 64 + ch * 8]);
        accS[0][f] = MFMA16(kf, qf[0][kc], accS[0][f], 0, 0, 0);
        accS[1][f] = MFMA16(kf, qf[1][kc], accS[1][f], 0, 0, 0);
      }
    }
    // online softmax per qm (row stats live in all 4 lanes sharing l15)
#pragma unroll
    for (int qm = 0; qm < 2; ++qm) {
      const int q0 = qbase + wave * 32 + qm * 16;
      float pl[16];
#pragma unroll
      for (int f = 0; f < 4; ++f)
#pragma unroll
        for (int r = 0; r < 4; ++r)
          pl[f * 4 + r] = accS[qm][f][r] * SCL;
      if (kbase + 63 > q0) {
        int qg = q0 + l15;
#pragma unroll
        for (int f = 0; f < 4; ++f)
#pragma unroll
          for (int r = 0; r < 4; ++r)
            if (kbase + f * 16 + (lq << 2) + r > qg) pl[f * 4 + r] = -1e30f;
      }
      float m0 = fmaxf(fmaxf(pl[0], pl[1]), fmaxf(pl[2], pl[3]));
      float m1 = fmaxf(fmaxf(pl[4], pl[5]), fmaxf(pl[6], pl[7]));
      float m2 = fmaxf(fmaxf(pl[8], pl[9]), fmaxf(pl[10], pl[11]));
      float m3 = fmaxf(fmaxf(pl[12], pl[13]), fmaxf(pl[14], pl[15]));
      float pmx = fmaxf(fmaxf(m0, m1), fmaxf(m2, m3));
      pmx = fmaxf(pmx, __shfl_xor(pmx, 16));
      pmx = fmaxf(pmx, __shfl_xor(pmx, 32));
      float mn = mrow[qm];
      if (!__all(pmx - mn <= 8.f)) {  // T13 defer-max (exp2 domain, THR=8)
        float mnew = fmaxf(mn, pmx);
        float al = exp2f(mn - mnew);
        mrow[qm] = mnew;
        lrow[qm] *= al;
        float alr[4];
#pragma unroll
        for (int r = 0; r < 4; ++r) alr[r] = __shfl(al, (lq << 2) + r);
#pragma unroll
        for (int ni = 0; ni < 8; ++ni) {
          f32x4 o = accO[qm][ni];
          o[0] *= alr[0]; o[1] *= alr[1]; o[2] *= alr[2]; o[3] *= alr[3];
          accO[qm][ni] = o;
        }
        mn = mnew;
      }
      float rs = 0.f;
#pragma unroll
      for (int i = 0; i < 16; ++i) {
        pl[i] = exp2f(pl[i] - mn);
        rs += pl[i];
      }
      rs += __shfl_xor(rs, 16);
      rs += __shfl_xor(rs, 32);
      lrow[qm] += rs;
      // P -> LDS (bf16), cvt_pk packed, b64 writes, 16B-chunk swizzle ^ (row&7)
      int prow = qm * 16 + l15;
#pragma unroll
      for (int f = 0; f < 4; ++f) {
        unsigned int plo, phi;
        asm("v_cvt_pk_bf16_f32 %0, %1, %2" : "=v"(plo) : "v"(pl[f * 4 + 0]), "v"(pl[f * 4 + 1]));
        asm("v_cvt_pk_bf16_f32 %0, %1, %2" : "=v"(phi) : "v"(pl[f * 4 + 2]), "v"(pl[f * 4 + 3]));
        int cs = ((f << 1) + (lq >> 1)) ^ (prow & 7);
        uint2 pk;
        pk.x = plo; pk.y = phi;
        *reinterpret_cast<uint2*>(&Ps[wave][prow * 64 + cs * 8 + ((lq & 1) << 2)]) = pk;
      }
    }
    // PV: O[q][dv] += P[q][kv] * Vt[dv][kv]^T
#pragma unroll
    for (int kc2 = 0; kc2 < 2; ++kc2) {
      bf16x8 vfr[8];
#pragma unroll
      for (int ni = 0; ni < 8; ++ni) {
        int dv = ni * 16 + l15;
        int vs = (kc2 * 4 + lq) ^ (dv & 7);
        vfr[ni] = *reinterpret_cast<const bf16x8*>(&VTs[dv * 64 + vs * 8]);
      }
#pragma unroll
      for (int qm = 0; qm < 2; ++qm) {
        int prow = qm * 16 + l15;
        int cs = (kc2 * 4 + lq) ^ (prow & 7);
        bf16x8 pf = *reinterpret_cast<const bf16x8*>(&Ps[wave][prow * 64 + cs * 8]);
#pragma unroll
        for (int ni = 0; ni < 8; ++ni)
          accO[qm][ni] = MFMA16(pf, vfr[ni], accO[qm][ni], 0, 0, 0);
      }
    }
  }
  // epilogue: normalize (fetch l per accO-row via bpermute) + store
#pragma unroll
  for (int qm = 0; qm < 2; ++qm) {
    float li[4];
#pragma unroll
    for (int r = 0; r < 4; ++r) li[r] = 1.f / __shfl(lrow[qm], (lq << 2) + r);
#pragma unroll
    for (int ni = 0; ni < 8; ++ni) {
      int dv = ni * 16 + l15;
#pragma unroll
      for (int r = 0; r < 4; ++r) {
        int row = qbase + wave * 32 + qm * 16 + (lq << 2) + r;
        Aw[(size_t)(b * Ss + row) * NV + h * DVv + dv] = f2b(accO[qm][ni][r] * li[r]);
      }
    }
  }
}

extern "C" void kernel_launch(void* const* d_in, const int* in_sizes, int n_in,
                              void* d_out, int out_size, void* d_ws, size_t ws_size,
                              hipStream_t stream) {
  (void)in_sizes; (void)n_in; (void)out_size; (void)ws_size;
  const float* x  = (const float*)d_in[0];
  const float* Wq = (const float*)d_in[1];
  const float* bq = (const float*)d_in[2];
  const float* Wk = (const float*)d_in[3];
  const float* bk = (const float*)d_in[4];
  const float* Wv = (const float*)d_in[5];
  const float* bv = (const float*)d_in[6];
  const float* Wo = (const float*)d_in[7];
  const float* bo = (const float*)d_in[8];
  float* out = (float*)d_out;

  unsigned short* ws = (unsigned short*)d_ws;
  unsigned short* xb  = ws;                    // 8388608  (x bf16 [8192][1024])
  unsigned short* WqT = xb  + 8388608;         // 1048576  ([H*DK][E])
  unsigned short* WkT = WqT + 1048576;         // 1048576
  unsigned short* WvT = WkT + 1048576;         // 2097152  ([H*DV][E])
  unsigned short* WoT = WvT + 2097152;         // 2097152  ([E][H*DV])
  unsigned short* Qw  = WoT + 2097152;         // 8388608  ([B,S,H,DK])
  unsigned short* Kw  = Qw  + 8388608;         // 8388608  ([B,S,H,DK])
  unsigned short* Vtw = Kw  + 8388608;         // 16777216 ([B,H,DV,S])
  unsigned short* Aw  = Vtw + 16777216;        // 16777216 ([B,S,H*DV])

  cast_x_kernel<<<dim3(8192), dim3(256), 0, stream>>>(x, xb, (Mm * Ee) / 4);

  transpose_cast_kernel<<<dim3(2, 32, 16), dim3(32, 8), 0, stream>>>(Wq, WqT, Ee, DKk);
  transpose_cast_kernel<<<dim3(2, 32, 16), dim3(32, 8), 0, stream>>>(Wk, WkT, Ee, DKk);
  transpose_cast_kernel<<<dim3(4, 32, 16), dim3(32, 8), 0, stream>>>(Wv, WvT, Ee, DVv);
  transpose_cast_kernel<<<dim3(32, 64, 1), dim3(32, 8), 0, stream>>>(Wo, WoT, NV, Ee);

  gemm_bt_kernel<0><<<dim3(64, 8),  dim3(256), 0, stream>>>(xb, WqT, bq, Qw, Mm, NQ, Ee);
  gemm_bt_kernel<0><<<dim3(64, 8),  dim3(256), 0, stream>>>(xb, WkT, bk, Kw, Mm, NQ, Ee);
  gemm_bt_kernel<2><<<dim3(64, 16), dim3(256), 0, stream>>>(xb, WvT, bv, Vtw, Mm, NV, Ee);

  attn2_kernel<<<dim3(16, 16, 4), dim3(256), 0, stream>>>(Qw, Kw, Vtw, Aw);

  gemm_bt_kernel<1><<<dim3(64, 8), dim3(256), 0, stream>>>(Aw, WoT, bo, out, Mm, NQ, NV);
}

// Round 3
// 370.669 us; speedup vs baseline: 3.0615x; 1.5892x over previous
//
#include <hip/hip_runtime.h>

typedef __bf16 bf16x8 __attribute__((ext_vector_type(8)));
typedef float f32x4 __attribute__((ext_vector_type(4)));

static constexpr int Bb = 4, Ss = 2048, Ee = 1024, Hh = 16, DKk = 64, DVv = 128;
static constexpr int Mm = Bb * Ss;   // 8192
static constexpr int NQ = Hh * DKk;  // 1024
static constexpr int NV = Hh * DVv;  // 2048

#define MFMA16 __builtin_amdgcn_mfma_f32_16x16x32_bf16

#define GLL16(g, l) __builtin_amdgcn_global_load_lds(                        \
    (const __attribute__((address_space(1))) void*)(g),                      \
    (__attribute__((address_space(3))) void*)(l), 16, 0, 0)

static __device__ __forceinline__ unsigned short f2b(float f) {
  unsigned int u = __float_as_uint(f);
  u += 0x7fffu + ((u >> 16) & 1u);
  return (unsigned short)(u >> 16);
}

__global__ __launch_bounds__(256) void cast_x_kernel(const float* __restrict__ in,
                                                     unsigned short* __restrict__ out, int n4) {
  int i = blockIdx.x * 256 + threadIdx.x;
  if (i >= n4) return;
  float4 v = reinterpret_cast<const float4*>(in)[i];
  ushort4 o;
  o.x = f2b(v.x); o.y = f2b(v.y); o.z = f2b(v.z); o.w = f2b(v.w);
  reinterpret_cast<ushort4*>(out)[i] = o;
}

// in: [Bt][R][C] f32  ->  out: [Bt][C][R] bf16
__global__ __launch_bounds__(256) void transpose_cast_kernel(const float* __restrict__ in,
                                                             unsigned short* __restrict__ out,
                                                             int R, int C) {
  __shared__ float tile[32][33];
  int c0 = blockIdx.x * 32, r0 = blockIdx.y * 32;
  const float* ip = in + (size_t)blockIdx.z * R * C;
  unsigned short* op = out + (size_t)blockIdx.z * R * C;
  int tx = threadIdx.x, ty = threadIdx.y;
#pragma unroll
  for (int i = 0; i < 32; i += 8)
    tile[ty + i][tx] = ip[(size_t)(r0 + ty + i) * C + (c0 + tx)];
  __syncthreads();
#pragma unroll
  for (int i = 0; i < 32; i += 8)
    op[(size_t)(c0 + ty + i) * R + (r0 + tx)] = f2b(tile[tx][ty + i]);
}

// C = A[M][K] * BT[N][K]^T + bias[N]; 128x128 tile, BK=32, 4 waves.
// OUTMODE: 1 = f32 [M][N]; 2 = bf16 Vt[B,H,DV,S]; 3 = bf16 head-major [B,H,S,64].
template <int OUTMODE>
__global__ __launch_bounds__(256) void gemm_bt_kernel(const unsigned short* __restrict__ A,
                                                      const unsigned short* __restrict__ BT,
                                                      const float* __restrict__ bias,
                                                      void* __restrict__ Cout,
                                                      int M, int N, int K) {
  __shared__ unsigned short As[128 * 32];
  __shared__ unsigned short Bs[128 * 32];
  const int tid = threadIdx.x;
  const int wave = tid >> 6, lane = tid & 63;
  const int wr = wave >> 1, wc = wave & 1;
  const int l15 = lane & 15, lq = lane >> 4;
  const int bm = blockIdx.x * 128, bn = blockIdx.y * 128;

  f32x4 acc[4][4] = {};

  const int m0c = tid >> 2;        // staging row within 64-row group
  const int kkc = (tid & 3) << 3;  // staging k-offset (elements)

  const unsigned short* ga0 = A + (size_t)(bm + m0c) * K + kkc;
  const unsigned short* ga1 = A + (size_t)(bm + 64 + m0c) * K + kkc;
  const unsigned short* gb0 = BT + (size_t)(bn + m0c) * K + kkc;
  const unsigned short* gb1 = BT + (size_t)(bn + 64 + m0c) * K + kkc;

  for (int k0 = 0; k0 < K; k0 += 32) {
    __syncthreads();  // previous tile's LDS reads complete
    GLL16(ga0 + k0, &As[(size_t)tid * 8]);
    GLL16(ga1 + k0, &As[(size_t)(tid + 256) * 8]);
    GLL16(gb0 + k0, &Bs[(size_t)tid * 8]);
    GLL16(gb1 + k0, &Bs[(size_t)(tid + 256) * 8]);
    __syncthreads();  // drains vmcnt: LDS tiles ready
    bf16x8 af[4], bfr[4];
#pragma unroll
    for (int mi = 0; mi < 4; ++mi)
      af[mi] = *reinterpret_cast<const bf16x8*>(&As[(wr * 64 + mi * 16 + l15) * 32 + (lq << 3)]);
#pragma unroll
    for (int ni = 0; ni < 4; ++ni)
      bfr[ni] = *reinterpret_cast<const bf16x8*>(&Bs[(wc * 64 + ni * 16 + l15) * 32 + (lq << 3)]);
#pragma unroll
    for (int mi = 0; mi < 4; ++mi)
#pragma unroll
      for (int ni = 0; ni < 4; ++ni)
        acc[mi][ni] = MFMA16(af[mi], bfr[ni], acc[mi][ni], 0, 0, 0);
  }
#pragma unroll
  for (int ni = 0; ni < 4; ++ni) {
    int col = bn + wc * 64 + ni * 16 + l15;
    float bs = bias[col];
#pragma unroll
    for (int mi = 0; mi < 4; ++mi) {
      int row0 = bm + wr * 64 + mi * 16 + (lq << 2);
      if (OUTMODE == 2) {
        int b_ = row0 >> 11, s0 = row0 & 2047;
        unsigned short* dst = (unsigned short*)Cout +
            ((size_t)((b_ * Hh + (col >> 7)) * DVv + (col & 127))) * Ss + s0;
        ushort4 o;
        o.x = f2b(acc[mi][ni][0] + bs);
        o.y = f2b(acc[mi][ni][1] + bs);
        o.z = f2b(acc[mi][ni][2] + bs);
        o.w = f2b(acc[mi][ni][3] + bs);
        *reinterpret_cast<ushort4*>(dst) = o;
      } else if (OUTMODE == 3) {
        int hh = col >> 6, d = col & 63;
#pragma unroll
        for (int r = 0; r < 4; ++r) {
          int row = row0 + r;
          int b_ = row >> 11, s0 = row & 2047;
          ((unsigned short*)Cout)[(((size_t)(b_ * Hh + hh) * Ss + s0) << 6) + d] =
              f2b(acc[mi][ni][r] + bs);
        }
      } else {
#pragma unroll
        for (int r = 0; r < 4; ++r)
          reinterpret_cast<float*>(Cout)[(size_t)(row0 + r) * N + col] = acc[mi][ni][r] + bs;
      }
    }
  }
}

// Barrier-free flash attention, causal. Qh/Kh: [B,H,S,64] bf16; Vt: [B,H,128,S] bf16;
// out Aw: [B,S,H*DV] bf16. Each wave owns q-blocks j and 63-j (32 rows each): 33 kv-iters
// per wave uniformly. No LDS, no __syncthreads; K/V read direct from global in MFMA layout.
__global__ __launch_bounds__(256, 2) void attn3_kernel(const unsigned short* __restrict__ Qh,
                                                       const unsigned short* __restrict__ Kh,
                                                       const unsigned short* __restrict__ Vt,
                                                       unsigned short* __restrict__ Aw) {
  const int bid = blockIdx.x;
  const int c = bid & 7, slot = bid >> 3;       // c -> XCD (round-robin dispatch)
  const int bh = c + ((slot >> 3) << 3);        // 8 blocks per (b,h), all on one XCD
  const int blk = slot & 7;
  const int b = bh >> 4, h = bh & 15;
  const int tid = threadIdx.x, wave = tid >> 6, lane = tid & 63;
  const int l15 = lane & 15, lq = lane >> 4;
  const int j = blk * 4 + wave;                 // 0..31
  const float SCL = 0.125f * 1.44269504088896f; // scale * log2(e)

  const unsigned short* Qsrc = Qh + (size_t)(b * Hh + h) * Ss * DKk;
  const unsigned short* Ksrc = Kh + (size_t)(b * Hh + h) * Ss * DKk;
  const unsigned short* Vsrc = Vt + (size_t)(b * Hh + h) * (size_t)DVv * Ss;
  unsigned short* Adst = Aw + (size_t)b * Ss * NV + h * DVv;

  const int srcA = l15 + ((lq & 1) << 5);  // lane holding kv0+{0..3} pack
  const int srcB = srcA + 16;              // lane holding kv0+{4..7} pack
  const bool selhi = (lq >> 1) & 1;        // pk register select (f parity)

  union PU { unsigned u[4]; bf16x8 v; };

#pragma unroll 1
  for (int ph = 0; ph < 2; ++ph) {
    const int qblk = ph ? (63 - j) : j;
    const int q0 = qblk * 32;
    const int nt = (qblk >> 1) + 1;

    bf16x8 qf[2][2];
#pragma unroll
    for (int qm = 0; qm < 2; ++qm) {
      const unsigned short* qp = Qsrc + (size_t)(q0 + qm * 16 + l15) * DKk + (lq << 3);
      qf[qm][0] = *reinterpret_cast<const bf16x8*>(qp);
      qf[qm][1] = *reinterpret_cast<const bf16x8*>(qp + 32);
    }

    f32x4 accO[2][8] = {};
    float mrow[2] = {-1e30f, -1e30f}, lrow[2] = {0.f, 0.f};

    for (int kt = 0; kt < nt; ++kt) {
      const int kbase = kt * 64;
      // K fragments: A-operand rows kv=f*16+l15, k-slice kc*32+lq*8
      bf16x8 kf[2][4];
#pragma unroll
      for (int f = 0; f < 4; ++f) {
        const unsigned short* kp = Ksrc + (size_t)(kbase + f * 16 + l15) * DKk + (lq << 3);
        kf[0][f] = *reinterpret_cast<const bf16x8*>(kp);
        kf[1][f] = *reinterpret_cast<const bf16x8*>(kp + 32);
      }
      // V^T fragments: B-operand cols dv=ni*16+l15, k-slice kc2*32+lq*8
      bf16x8 vf[2][8];
#pragma unroll
      for (int ni = 0; ni < 8; ++ni) {
        const unsigned short* vp = Vsrc + (size_t)(ni * 16 + l15) * Ss + kbase + (lq << 3);
        vf[0][ni] = *reinterpret_cast<const bf16x8*>(vp);
        vf[1][ni] = *reinterpret_cast<const bf16x8*>(vp + 32);
      }
      // QK^T swapped: accS[qm][f]: row kv_local=lq*4+r (in f-group), col q=l15
      f32x4 accS[2][4] = {};
      __builtin_amdgcn_s_setprio(1);
#pragma unroll
      for (int kc = 0; kc < 2; ++kc)
#pragma unroll
        for (int f = 0; f < 4; ++f) {
          accS[0][f] = MFMA16(kf[kc][f], qf[0][kc], accS[0][f], 0, 0, 0);
          accS[1][f] = MFMA16(kf[kc][f], qf[1][kc], accS[1][f], 0, 0, 0);
        }
      __builtin_amdgcn_s_setprio(0);

      bf16x8 pfq[2][2];
#pragma unroll
      for (int qm = 0; qm < 2; ++qm) {
        const int q0m = q0 + qm * 16;
        float pl[16];
#pragma unroll
        for (int f = 0; f < 4; ++f)
#pragma unroll
          for (int r = 0; r < 4; ++r)
            pl[f * 4 + r] = accS[qm][f][r] * SCL;
        if (kbase + 63 > q0m) {
          int qg = q0m + l15;
#pragma unroll
          for (int f = 0; f < 4; ++f)
#pragma unroll
            for (int r = 0; r < 4; ++r)
              if (kbase + f * 16 + (lq << 2) + r > qg) pl[f * 4 + r] = -1e30f;
        }
        float m0 = fmaxf(fmaxf(pl[0], pl[1]), fmaxf(pl[2], pl[3]));
        float m1 = fmaxf(fmaxf(pl[4], pl[5]), fmaxf(pl[6], pl[7]));
        float m2 = fmaxf(fmaxf(pl[8], pl[9]), fmaxf(pl[10], pl[11]));
        float m3 = fmaxf(fmaxf(pl[12], pl[13]), fmaxf(pl[14], pl[15]));
        float pmx = fmaxf(fmaxf(m0, m1), fmaxf(m2, m3));
        pmx = fmaxf(pmx, __shfl_xor(pmx, 16));
        pmx = fmaxf(pmx, __shfl_xor(pmx, 32));
        float mn = mrow[qm];
        if (!__all(pmx - mn <= 8.f)) {  // T13 defer-max
          float mnew = fmaxf(mn, pmx);
          float al = exp2f(mn - mnew);
          mrow[qm] = mnew;
          lrow[qm] *= al;
          float alr[4];
#pragma unroll
          for (int r = 0; r < 4; ++r) alr[r] = __shfl(al, (lq << 2) + r);
#pragma unroll
          for (int ni = 0; ni < 8; ++ni) {
            f32x4 o = accO[qm][ni];
            o[0] *= alr[0]; o[1] *= alr[1]; o[2] *= alr[2]; o[3] *= alr[3];
            accO[qm][ni] = o;
          }
          mn = mnew;
        }
        float rs = 0.f;
#pragma unroll
        for (int i = 0; i < 16; ++i) {
          pl[i] = exp2f(pl[i] - mn);
          rs += pl[i];
        }
        rs += __shfl_xor(rs, 16);
        rs += __shfl_xor(rs, 32);
        lrow[qm] += rs;
        // pack P to bf16 pairs: pk0[f]=kv(f*16+lq*4+{0,1}), pk1[f]=+{2,3}
        unsigned pk0[4], pk1[4];
#pragma unroll
        for (int f = 0; f < 4; ++f) {
          asm("v_cvt_pk_bf16_f32 %0, %1, %2" : "=v"(pk0[f]) : "v"(pl[f * 4 + 0]), "v"(pl[f * 4 + 1]));
          asm("v_cvt_pk_bf16_f32 %0, %1, %2" : "=v"(pk1[f]) : "v"(pl[f * 4 + 2]), "v"(pl[f * 4 + 3]));
        }
        // exchange to PV A-operand: lane needs kv = kc2*32+lq*8+{0..7}
#pragma unroll
        for (int kc2 = 0; kc2 < 2; ++kc2) {
          PU u;
          unsigned a0 = __shfl((int)pk0[2 * kc2], srcA), b0 = __shfl((int)pk0[2 * kc2 + 1], srcA);
          u.u[0] = selhi ? b0 : a0;
          unsigned a1 = __shfl((int)pk1[2 * kc2], srcA), b1 = __shfl((int)pk1[2 * kc2 + 1], srcA);
          u.u[1] = selhi ? b1 : a1;
          unsigned a2 = __shfl((int)pk0[2 * kc2], srcB), b2 = __shfl((int)pk0[2 * kc2 + 1], srcB);
          u.u[2] = selhi ? b2 : a2;
          unsigned a3 = __shfl((int)pk1[2 * kc2], srcB), b3 = __shfl((int)pk1[2 * kc2 + 1], srcB);
          u.u[3] = selhi ? b3 : a3;
          pfq[qm][kc2] = u.v;
        }
      }
      // PV: O[q][dv] += P[q][kv] * V^T[dv][kv]^T
      __builtin_amdgcn_s_setprio(1);
#pragma unroll
      for (int kc2 = 0; kc2 < 2; ++kc2)
#pragma unroll
        for (int qm = 0; qm < 2; ++qm)
#pragma unroll
          for (int ni = 0; ni < 8; ++ni)
            accO[qm][ni] = MFMA16(pfq[qm][kc2], vf[kc2][ni], accO[qm][ni], 0, 0, 0);
      __builtin_amdgcn_s_setprio(0);
    }
    // epilogue: normalize + store
#pragma unroll
    for (int qm = 0; qm < 2; ++qm) {
      float li[4];
#pragma unroll
      for (int r = 0; r < 4; ++r) li[r] = 1.f / __shfl(lrow[qm], (lq << 2) + r);
#pragma unroll
      for (int ni = 0; ni < 8; ++ni) {
        int dv = ni * 16 + l15;
#pragma unroll
        for (int r = 0; r < 4; ++r) {
          int row = q0 + qm * 16 + (lq << 2) + r;
          Adst[(size_t)row * NV + dv] = f2b(accO[qm][ni][r] * li[r]);
        }
      }
    }
  }
}

extern "C" void kernel_launch(void* const* d_in, const int* in_sizes, int n_in,
                              void* d_out, int out_size, void* d_ws, size_t ws_size,
                              hipStream_t stream) {
  (void)in_sizes; (void)n_in; (void)out_size; (void)ws_size;
  const float* x  = (const float*)d_in[0];
  const float* Wq = (const float*)d_in[1];
  const float* bq = (const float*)d_in[2];
  const float* Wk = (const float*)d_in[3];
  const float* bk = (const float*)d_in[4];
  const float* Wv = (const float*)d_in[5];
  const float* bv = (const float*)d_in[6];
  const float* Wo = (const float*)d_in[7];
  const float* bo = (const float*)d_in[8];
  float* out = (float*)d_out;

  unsigned short* ws = (unsigned short*)d_ws;
  unsigned short* xb  = ws;                    // 8388608  (x bf16 [8192][1024])
  unsigned short* WqT = xb  + 8388608;         // 1048576  ([H*DK][E])
  unsigned short* WkT = WqT + 1048576;         // 1048576
  unsigned short* WvT = WkT + 1048576;         // 2097152  ([H*DV][E])
  unsigned short* WoT = WvT + 2097152;         // 2097152  ([E][H*DV])
  unsigned short* Qw  = WoT + 2097152;         // 8388608  ([B,H,S,64])
  unsigned short* Kw  = Qw  + 8388608;         // 8388608  ([B,H,S,64])
  unsigned short* Vtw = Kw  + 8388608;         // 16777216 ([B,H,128,S])
  unsigned short* Aw  = Vtw + 16777216;        // 16777216 ([B,S,H*DV])

  cast_x_kernel<<<dim3(8192), dim3(256), 0, stream>>>(x, xb, (Mm * Ee) / 4);

  transpose_cast_kernel<<<dim3(2, 32, 16), dim3(32, 8), 0, stream>>>(Wq, WqT, Ee, DKk);
  transpose_cast_kernel<<<dim3(2, 32, 16), dim3(32, 8), 0, stream>>>(Wk, WkT, Ee, DKk);
  transpose_cast_kernel<<<dim3(4, 32, 16), dim3(32, 8), 0, stream>>>(Wv, WvT, Ee, DVv);
  transpose_cast_kernel<<<dim3(32, 64, 1), dim3(32, 8), 0, stream>>>(Wo, WoT, NV, Ee);

  gemm_bt_kernel<3><<<dim3(64, 8),  dim3(256), 0, stream>>>(xb, WqT, bq, Qw, Mm, NQ, Ee);
  gemm_bt_kernel<3><<<dim3(64, 8),  dim3(256), 0, stream>>>(xb, WkT, bk, Kw, Mm, NQ, Ee);
  gemm_bt_kernel<2><<<dim3(64, 16), dim3(256), 0, stream>>>(xb, WvT, bv, Vtw, Mm, NV, Ee);

  attn3_kernel<<<dim3(512), dim3(256), 0, stream>>>(Qw, Kw, Vtw, Aw);

  gemm_bt_kernel<1><<<dim3(64, 8), dim3(256), 0, stream>>>(Aw, WoT, bo, out, Mm, NQ, NV);
}